// Round 7
// baseline (480.059 us; speedup 1.0000x reference)
//
#include <hip/hip_runtime.h>
#include <stdint.h>

#define T_LEN 2048
#define BATCH 64
#define I_DIM 256
#define H_DIM 256
#define N3    768
#define M_ROWS (T_LEN*BATCH)
#define L2E 1.4426950408889634f

typedef _Float16 f16;
typedef __attribute__((ext_vector_type(4))) float  f32x4;
typedef __attribute__((ext_vector_type(2))) _Float16 f16x2;
typedef __attribute__((ext_vector_type(8))) _Float16 f16x8;

__device__ __forceinline__ f16x2 u2h(unsigned int u) {
    union { unsigned int u; f16x2 h; } c; c.u = u; return c.h;
}

// ---------------------------------------------------------------------------
// Kernel A: X [M,256] f32 -> f16, pre-XOR-swizzled in 16B units within each
// 8-unit (64-f16) group: out unit gu holds source unit (gu&~7)|((gu&7)^(m&7)).
// The GEMM global_load_lds's rows linearly and XOR-swizzles on ds_read.
// ---------------------------------------------------------------------------
__global__ __launch_bounds__(256) void convert_x(const float* __restrict__ X,
                                                 f16* __restrict__ Xs) {
    const int U = M_ROWS * 32;                 // 16B units
    for (int u = blockIdx.x * 256 + threadIdx.x; u < U; u += 2048 * 256) {
        int m = u >> 5, gu = u & 31;
        int su = (gu & 24) | ((gu & 7) ^ (m & 7));
        const float* src = X + (size_t)m * 256 + su * 8;
        f32x4 a = *(const f32x4*)src;
        f32x4 b = *(const f32x4*)(src + 4);
        f16x8 v;
        #pragma unroll
        for (int e = 0; e < 4; ++e) { v[e] = (f16)a[e]; v[4+e] = (f16)b[e]; }
        *(f16x8*)(Xs + (size_t)m * 256 + gu * 8) = v;
    }
}

// ---------------------------------------------------------------------------
// Kernel B: W_ih [768,256] f32 -> f16, gate scale baked in (-L2E r,z; -2L2E n),
// same pre-XOR-swizzle.
// ---------------------------------------------------------------------------
__global__ __launch_bounds__(256) void convert_w(const float* __restrict__ W,
                                                 f16* __restrict__ Ws) {
    int u = blockIdx.x * 256 + threadIdx.x;    // 24576 units
    int n = u >> 5, gu = u & 31;
    float scale = (n < 512) ? -L2E : -2.0f * L2E;
    int su = (gu & 24) | ((gu & 7) ^ (n & 7));
    const float* src = W + (size_t)n * 256 + su * 8;
    f32x4 a = *(const f32x4*)src;
    f32x4 b = *(const f32x4*)(src + 4);
    f16x8 v;
    #pragma unroll
    for (int e = 0; e < 4; ++e) { v[e] = (f16)(a[e]*scale); v[4+e] = (f16)(b[e]*scale); }
    *(f16x8*)(Ws + (size_t)n * 256 + gu * 8) = v;
}

// ---------------------------------------------------------------------------
// Kernel C: gx = Xs * Ws^T, f16 MFMA, m97 structure. BM=BN=128, BK=64,
// 256 thr (2x2 waves, 64x64 each), glds-direct both operands, 32KiB LDS,
// XOR-swizzled ds_read_b128. Epilogue: LDS shuffle -> packed P2 layout
// [t/2][b][gh][2] f16 with 512B-contiguous runs per b.
// ---------------------------------------------------------------------------
__global__ __launch_bounds__(256, 4) void gemm_gx(
        const f16* __restrict__ Xs,
        const f16* __restrict__ Ws,
        f16* __restrict__ gxP) {
    __shared__ union {
        struct { f16 A[128*64]; f16 B[128*64]; } s;   // 16KB + 16KB
        f16 C[64*128*2];                               // 32KB epilogue
    } u;

    int wg   = blockIdx.x;                  // 6144 blocks
    int orig = (wg & 7) * 768 + (wg >> 3);  // XCD-chunked (6144%8==0)
    int mblk = orig / 6, nblk = orig - mblk * 6;
    int m0 = mblk * 128, n0 = nblk * 128;

    int tid = threadIdx.x, lane = tid & 63, wid = tid >> 6;
    int wm = wid >> 1, wn = wid & 1;

    f32x4 acc[4][4] = {};

    for (int kb = 0; kb < 4; ++kb) {
        if (kb) __syncthreads();            // prev frag reads done
        // glds: A tile 16KB (4 rounds) + B tile 16KB (4 rounds), linear LDS
        #pragma unroll
        for (int rd = 0; rd < 4; ++rd) {
            int uu = rd * 256 + tid;        // 16B unit in tile
            int row = uu >> 3, pl = uu & 7;
            const f16* ga = Xs + (size_t)(m0 + row) * 256 + kb * 64 + pl * 8;
            __builtin_amdgcn_global_load_lds(
                (const __attribute__((address_space(1))) void*)ga,
                (__attribute__((address_space(3))) void*)(u.s.A + uu * 8), 16, 0, 0);
        }
        #pragma unroll
        for (int rd = 0; rd < 4; ++rd) {
            int uu = rd * 256 + tid;
            int row = uu >> 3, pl = uu & 7;
            const f16* gb = Ws + (size_t)(n0 + row) * 256 + kb * 64 + pl * 8;
            __builtin_amdgcn_global_load_lds(
                (const __attribute__((address_space(1))) void*)gb,
                (__attribute__((address_space(3))) void*)(u.s.B + uu * 8), 16, 0, 0);
        }
        __syncthreads();                    // vmcnt(0) drain before barrier
        #pragma unroll
        for (int kk = 0; kk < 2; ++kk) {
            int c16 = kk * 4 + (lane >> 4);
            f16x8 af[4], bf[4];
            #pragma unroll
            for (int mi = 0; mi < 4; ++mi) {
                int row = wm*64 + mi*16 + (lane & 15);
                af[mi] = *(const f16x8*)((const char*)u.s.A + row*128 + ((c16 ^ (row & 7)) * 16));
            }
            #pragma unroll
            for (int ni = 0; ni < 4; ++ni) {
                int row = wn*64 + ni*16 + (lane & 15);
                bf[ni] = *(const f16x8*)((const char*)u.s.B + row*128 + ((c16 ^ (row & 7)) * 16));
            }
            #pragma unroll
            for (int mi = 0; mi < 4; ++mi)
              #pragma unroll
              for (int ni = 0; ni < 4; ++ni)
                acc[mi][ni] = __builtin_amdgcn_mfma_f32_16x16x32_f16(af[mi], bf[ni], acc[mi][ni], 0,0,0);
        }
    }

    // ---- epilogue: frags -> Cl[b][ghl][tl] -> packed global ----
    __syncthreads();                        // last frag reads done
    #pragma unroll
    for (int mi = 0; mi < 4; ++mi) {
        int rr = mi*16 + (lane >> 4)*4;     // r = wm*64 + rr + j; b=rr+j, tl=wm
        #pragma unroll
        for (int ni = 0; ni < 4; ++ni) {
            int c = wn*64 + ni*16 + (lane & 15);
            #pragma unroll
            for (int j = 0; j < 4; ++j)
                u.C[(rr + j)*256 + c*2 + wm] = (f16)acc[mi][ni][j];
        }
    }
    __syncthreads();
    #pragma unroll
    for (int i = 0; i < 8; ++i) {
        int uu = i*256 + tid, b = uu >> 5, q = uu & 31;   // 512B per b
        f16x8 v = *(const f16x8*)(u.C + b*256 + q*8);
        *(f16x8*)(gxP + (size_t)(mblk*64 + b)*1536 + n0*2 + q*8) = v;
    }
}

// ---------------------------------------------------------------------------
// Kernel D: diagonal-GRU scan over packed P2[t/2][b][gh][2] (f16).
// 16384 chains, one lane each (256 waves, 1/CU).
// Round-6 forensics: plain-C++ prefetch was destroyed by IR-level sinking
// (VGPR=40 < the 65 a double-buffer needs; sched_barrier is IntrNoMem so IR
// moves loads across it). Fix: inline-asm global_load_dword (opaque to all
// movers; compiler emits NO waitcnt for asm loads) + manual
// s_waitcnt vmcnt(24) + sched_barrier(0) (rule #18). vmcnt(24) is robust:
// batch k+1 (24 loads) always issues before the wait, vmcnt retires in
// order, so <=24 outstanding implies batch k fully arrived regardless of
// where the 16 output stores land in the queue.
// ---------------------------------------------------------------------------
__global__ __launch_bounds__(64, 1) void indgru_scan(
        const f16* __restrict__ gxP, const float* __restrict__ bih,
        const float* __restrict__ bhh, const float* __restrict__ whh,
        float* __restrict__ out) {
    int lane = threadIdx.x;
    int b = blockIdx.x >> 2;
    int h = (blockIdx.x & 3) * 64 + lane;

    float whr = -L2E  * whh[h];
    float whz = -L2E  * whh[H_DIM + h];
    float whn = -2.0f*L2E * whh[2*H_DIM + h];
    float cr  = -L2E  * (bih[h] + bhh[h]);
    float cz  = -L2E  * (bih[H_DIM+h] + bhh[H_DIM+h]);
    float cn  = -2.0f*L2E * bih[2*H_DIM+h];
    float bhn = -2.0f*L2E * bhh[2*H_DIM+h];

    const size_t stp = (size_t)BATCH * N3 * 2;   // f16 per t-pair row (98304)
    const size_t so  = (size_t)BATCH * H_DIM;
    float* po = out + (size_t)b * H_DIM + h;

    // 8 per-q address cursors (64-bit VGPR pairs in the asm), batch stride
    // = 8 t-pair rows = 8*stp f16.
    const f16* ad[8];
    #pragma unroll
    for (int q = 0; q < 8; ++q)
        ad[q] = gxP + (size_t)b * 1536 + h * 2 + (size_t)q * stp;

    unsigned int Ar[8], Az[8], An[8], Br[8], Bz[8], Bn[8];
    float hv = 0.f;

// Issue one 24-load batch (8 t-pairs x 3 gates) and advance cursors.
#define LOADB(R, Z, N) do {                                              \
        _Pragma("unroll")                                                \
        for (int _q = 0; _q < 8; ++_q) {                                 \
            asm volatile("global_load_dword %0, %1, off"                 \
                         : "=v"(R[_q]) : "v"(ad[_q]));                   \
            asm volatile("global_load_dword %0, %1, off offset:1024"     \
                         : "=v"(Z[_q]) : "v"(ad[_q]));                   \
            asm volatile("global_load_dword %0, %1, off offset:2048"     \
                         : "=v"(N[_q]) : "v"(ad[_q]));                   \
        }                                                                \
        _Pragma("unroll")                                                \
        for (int _q = 0; _q < 8; ++_q) ad[_q] += 8 * stp;                \
    } while (0)

// Wait until the PREVIOUS batch retired (24 newer loads allowed in flight),
// then fence so dependent v_cvt can't hoist above the wait.
#define VWAIT24 do { asm volatile("s_waitcnt vmcnt(24)" ::: "memory");   \
                     __builtin_amdgcn_sched_barrier(0); } while (0)
#define VWAIT0  do { asm volatile("s_waitcnt vmcnt(0)"  ::: "memory");   \
                     __builtin_amdgcn_sched_barrier(0); } while (0)

#define PROC16(R, Z, N) do {                                        \
        _Pragma("unroll")                                           \
        for (int _q = 0; _q < 8; ++_q) {                            \
            f16x2 rv = u2h(R[_q]), zv = u2h(Z[_q]), nv = u2h(N[_q]);\
            _Pragma("unroll")                                       \
            for (int _j = 0; _j < 2; ++_j) {                        \
                float ur = (float)rv[_j] + cr;                      \
                float uz = (float)zv[_j] + cz;                      \
                float un = (float)nv[_j] + cn;                      \
                float er = __builtin_amdgcn_exp2f(fmaf(whr, hv, ur)); \
                float r  = __builtin_amdgcn_rcpf(1.f + er);         \
                float ez = __builtin_amdgcn_exp2f(fmaf(whz, hv, uz)); \
                float z  = __builtin_amdgcn_rcpf(1.f + ez);         \
                float mn = fmaf(whn, hv, bhn);                      \
                float en = __builtin_amdgcn_exp2f(fmaf(r, mn, un)); \
                float q  = __builtin_amdgcn_rcpf(1.f + en);         \
                float hp1 = hv + 1.f;                               \
                hv = fmaf(z, fmaf(-2.f, q, hp1), fmaf(2.f, q, -1.f)); \
                *po = hv; po += so;                                 \
            }                                                       \
        }                                                           \
    } while (0)

    LOADB(Ar, Az, An);                 // batch 0
    for (int i = 0; i < 63; ++i) {
        LOADB(Br, Bz, Bn);             // batch 2i+1
        VWAIT24;                       // batch 2i arrived
        PROC16(Ar, Az, An);
        LOADB(Ar, Az, An);             // batch 2i+2
        VWAIT24;                       // batch 2i+1 arrived
        PROC16(Br, Bz, Bn);
    }
    LOADB(Br, Bz, Bn);                 // batch 127
    VWAIT24;
    PROC16(Ar, Az, An);                // batch 126
    VWAIT0;
    PROC16(Br, Bz, Bn);                // batch 127

    out[(size_t)T_LEN * so + (size_t)b * H_DIM + h] = hv;   // h_n
#undef LOADB
#undef VWAIT24
#undef VWAIT0
#undef PROC16
}

// ---------------------------------------------------------------------------
extern "C" void kernel_launch(void* const* d_in, const int* in_sizes, int n_in,
                              void* d_out, int out_size, void* d_ws, size_t ws_size,
                              hipStream_t stream) {
    const float* x   = (const float*)d_in[0];
    const float* Wih = (const float*)d_in[1];
    const float* bih = (const float*)d_in[2];
    const float* bhh = (const float*)d_in[3];
    const float* whh = (const float*)d_in[4];
    float* out = (float*)d_out;

    char* ws = (char*)d_ws;
    f16* gxP = (f16*)ws;                                       // 192 MiB packed
    f16* Xs  = (f16*)(ws + (size_t)M_ROWS*N3*sizeof(f16));     // 64 MiB
    f16* Wsc = Xs + (size_t)M_ROWS*I_DIM;                      // 384 KiB

    convert_x<<<2048, 256, 0, stream>>>(x, Xs);
    convert_w<<<(N3*I_DIM/8)/256, 256, 0, stream>>>(Wih, Wsc);
    gemm_gx<<<(M_ROWS/128)*(N3/128), 256, 0, stream>>>(Xs, Wsc, gxP);
    indgru_scan<<<BATCH*(H_DIM/64), 64, 0, stream>>>(gxP, bih, bhh, whh, out);
}

// Round 8
// 476.899 us; speedup vs baseline: 1.0066x; 1.0066x over previous
//
#include <hip/hip_runtime.h>
#include <stdint.h>

#define T_LEN 2048
#define BATCH 64
#define I_DIM 256
#define H_DIM 256
#define N3    768
#define M_ROWS (T_LEN*BATCH)
#define L2E 1.4426950408889634f

typedef _Float16 f16;
typedef __attribute__((ext_vector_type(4))) float  f32x4;
typedef __attribute__((ext_vector_type(2))) _Float16 f16x2;
typedef __attribute__((ext_vector_type(8))) _Float16 f16x8;

__device__ __forceinline__ f16x2 u2h(unsigned int u) {
    union { unsigned int u; f16x2 h; } c; c.u = u; return c.h;
}

// ---------------------------------------------------------------------------
// Kernel A: X [M,256] f32 -> f16, pre-XOR-swizzled in 16B units within each
// 8-unit (64-f16) group: out unit gu holds source unit (gu&~7)|((gu&7)^(m&7)).
// The GEMM global_load_lds's rows linearly and XOR-swizzles on ds_read.
// ---------------------------------------------------------------------------
__global__ __launch_bounds__(256) void convert_x(const float* __restrict__ X,
                                                 f16* __restrict__ Xs) {
    const int U = M_ROWS * 32;                 // 16B units
    for (int u = blockIdx.x * 256 + threadIdx.x; u < U; u += 2048 * 256) {
        int m = u >> 5, gu = u & 31;
        int su = (gu & 24) | ((gu & 7) ^ (m & 7));
        const float* src = X + (size_t)m * 256 + su * 8;
        f32x4 a = *(const f32x4*)src;
        f32x4 b = *(const f32x4*)(src + 4);
        f16x8 v;
        #pragma unroll
        for (int e = 0; e < 4; ++e) { v[e] = (f16)a[e]; v[4+e] = (f16)b[e]; }
        *(f16x8*)(Xs + (size_t)m * 256 + gu * 8) = v;
    }
}

// ---------------------------------------------------------------------------
// Kernel B: W_ih [768,256] f32 -> f16, gate scale baked in (-L2E r,z; -2L2E n),
// same pre-XOR-swizzle.
// ---------------------------------------------------------------------------
__global__ __launch_bounds__(256) void convert_w(const float* __restrict__ W,
                                                 f16* __restrict__ Ws) {
    int u = blockIdx.x * 256 + threadIdx.x;    // 24576 units
    int n = u >> 5, gu = u & 31;
    float scale = (n < 512) ? -L2E : -2.0f * L2E;
    int su = (gu & 24) | ((gu & 7) ^ (n & 7));
    const float* src = W + (size_t)n * 256 + su * 8;
    f32x4 a = *(const f32x4*)src;
    f32x4 b = *(const f32x4*)(src + 4);
    f16x8 v;
    #pragma unroll
    for (int e = 0; e < 4; ++e) { v[e] = (f16)(a[e]*scale); v[4+e] = (f16)(b[e]*scale); }
    *(f16x8*)(Ws + (size_t)n * 256 + gu * 8) = v;
}

// ---------------------------------------------------------------------------
// Kernel C: gx = Xs * Ws^T, f16 MFMA, m97 structure. BM=BN=128, BK=64,
// 256 thr (2x2 waves, 64x64 each), glds-direct both operands, 32KiB LDS,
// XOR-swizzled ds_read_b128. Epilogue: LDS shuffle -> packed P2 layout
// [t/2][b][gh][2] f16 with 512B-contiguous runs per b.
// ---------------------------------------------------------------------------
__global__ __launch_bounds__(256, 4) void gemm_gx(
        const f16* __restrict__ Xs,
        const f16* __restrict__ Ws,
        f16* __restrict__ gxP) {
    __shared__ union {
        struct { f16 A[128*64]; f16 B[128*64]; } s;   // 16KB + 16KB
        f16 C[64*128*2];                               // 32KB epilogue
    } u;

    int wg   = blockIdx.x;                  // 6144 blocks
    int orig = (wg & 7) * 768 + (wg >> 3);  // XCD-chunked (6144%8==0)
    int mblk = orig / 6, nblk = orig - mblk * 6;
    int m0 = mblk * 128, n0 = nblk * 128;

    int tid = threadIdx.x, lane = tid & 63, wid = tid >> 6;
    int wm = wid >> 1, wn = wid & 1;

    f32x4 acc[4][4] = {};

    for (int kb = 0; kb < 4; ++kb) {
        if (kb) __syncthreads();            // prev frag reads done
        // glds: A tile 16KB (4 rounds) + B tile 16KB (4 rounds), linear LDS
        #pragma unroll
        for (int rd = 0; rd < 4; ++rd) {
            int uu = rd * 256 + tid;        // 16B unit in tile
            int row = uu >> 3, pl = uu & 7;
            const f16* ga = Xs + (size_t)(m0 + row) * 256 + kb * 64 + pl * 8;
            __builtin_amdgcn_global_load_lds(
                (const __attribute__((address_space(1))) void*)ga,
                (__attribute__((address_space(3))) void*)(u.s.A + uu * 8), 16, 0, 0);
        }
        #pragma unroll
        for (int rd = 0; rd < 4; ++rd) {
            int uu = rd * 256 + tid;
            int row = uu >> 3, pl = uu & 7;
            const f16* gb = Ws + (size_t)(n0 + row) * 256 + kb * 64 + pl * 8;
            __builtin_amdgcn_global_load_lds(
                (const __attribute__((address_space(1))) void*)gb,
                (__attribute__((address_space(3))) void*)(u.s.B + uu * 8), 16, 0, 0);
        }
        __syncthreads();                    // vmcnt(0) drain before barrier
        #pragma unroll
        for (int kk = 0; kk < 2; ++kk) {
            int c16 = kk * 4 + (lane >> 4);
            f16x8 af[4], bf[4];
            #pragma unroll
            for (int mi = 0; mi < 4; ++mi) {
                int row = wm*64 + mi*16 + (lane & 15);
                af[mi] = *(const f16x8*)((const char*)u.s.A + row*128 + ((c16 ^ (row & 7)) * 16));
            }
            #pragma unroll
            for (int ni = 0; ni < 4; ++ni) {
                int row = wn*64 + ni*16 + (lane & 15);
                bf[ni] = *(const f16x8*)((const char*)u.s.B + row*128 + ((c16 ^ (row & 7)) * 16));
            }
            #pragma unroll
            for (int mi = 0; mi < 4; ++mi)
              #pragma unroll
              for (int ni = 0; ni < 4; ++ni)
                acc[mi][ni] = __builtin_amdgcn_mfma_f32_16x16x32_f16(af[mi], bf[ni], acc[mi][ni], 0,0,0);
        }
    }

    // ---- epilogue: frags -> Cl[b][ghl][tl] -> packed global ----
    __syncthreads();                        // last frag reads done
    #pragma unroll
    for (int mi = 0; mi < 4; ++mi) {
        int rr = mi*16 + (lane >> 4)*4;     // r = wm*64 + rr + j; b=rr+j, tl=wm
        #pragma unroll
        for (int ni = 0; ni < 4; ++ni) {
            int c = wn*64 + ni*16 + (lane & 15);
            #pragma unroll
            for (int j = 0; j < 4; ++j)
                u.C[(rr + j)*256 + c*2 + wm] = (f16)acc[mi][ni][j];
        }
    }
    __syncthreads();
    #pragma unroll
    for (int i = 0; i < 8; ++i) {
        int uu = i*256 + tid, b = uu >> 5, q = uu & 31;   // 512B per b
        f16x8 v = *(const f16x8*)(u.C + b*256 + q*8);
        *(f16x8*)(gxP + (size_t)(mblk*64 + b)*1536 + n0*2 + q*8) = v;
    }
}

// ---------------------------------------------------------------------------
// Kernel D: diagonal-GRU scan over packed P2[t/2][b][gh][2] (f16).
// 16384 chains, one lane each (256 waves, 1/CU). Inline-asm loads +
// hand-placed waits (round 6/7 forensics: plain-C++ prefetch gets destroyed).
// Round-7 forensics: vmcnt(24) also waited on the 16 OUTPUT STORES of the
// just-finished PROC16 (in-order vmcnt queue: [L(k) 24, S(k-1) 16, L(k+1) 24];
// vmcnt(24) retires the oldest 40 = loads+stores; store write-ack ~300-500cy
// issued ~0-150cy earlier = stall every batch). Fix: vmcnt(40) lets the 16
// stores + 24 new loads float while still (in-order retirement) guaranteeing
// batch-k loads arrived. First wait peeled at vmcnt(24): its queue is only
// 48 deep, vmcnt(40) there would admit 16 unarrived loads.
// ---------------------------------------------------------------------------
__global__ __launch_bounds__(64, 1) void indgru_scan(
        const f16* __restrict__ gxP, const float* __restrict__ bih,
        const float* __restrict__ bhh, const float* __restrict__ whh,
        float* __restrict__ out) {
    int lane = threadIdx.x;
    int b = blockIdx.x >> 2;
    int h = (blockIdx.x & 3) * 64 + lane;

    float whr = -L2E  * whh[h];
    float whz = -L2E  * whh[H_DIM + h];
    float whn = -2.0f*L2E * whh[2*H_DIM + h];
    float cr  = -L2E  * (bih[h] + bhh[h]);
    float cz  = -L2E  * (bih[H_DIM+h] + bhh[H_DIM+h]);
    float cn  = -2.0f*L2E * bih[2*H_DIM+h];
    float bhn = -2.0f*L2E * bhh[2*H_DIM+h];

    const size_t stp = (size_t)BATCH * N3 * 2;   // f16 per t-pair row (98304)
    const size_t so  = (size_t)BATCH * H_DIM;
    float* po = out + (size_t)b * H_DIM + h;

    const f16* ad[8];
    #pragma unroll
    for (int q = 0; q < 8; ++q)
        ad[q] = gxP + (size_t)b * 1536 + h * 2 + (size_t)q * stp;

    unsigned int Ar[8], Az[8], An[8], Br[8], Bz[8], Bn[8];
    float hv = 0.f;

#define LOADB(R, Z, N) do {                                              \
        _Pragma("unroll")                                                \
        for (int _q = 0; _q < 8; ++_q) {                                 \
            asm volatile("global_load_dword %0, %1, off"                 \
                         : "=v"(R[_q]) : "v"(ad[_q]));                   \
            asm volatile("global_load_dword %0, %1, off offset:1024"     \
                         : "=v"(Z[_q]) : "v"(ad[_q]));                   \
            asm volatile("global_load_dword %0, %1, off offset:2048"     \
                         : "=v"(N[_q]) : "v"(ad[_q]));                   \
        }                                                                \
        _Pragma("unroll")                                                \
        for (int _q = 0; _q < 8; ++_q) ad[_q] += 8 * stp;                \
    } while (0)

#define VWAIT24 do { asm volatile("s_waitcnt vmcnt(24)" ::: "memory");   \
                     __builtin_amdgcn_sched_barrier(0); } while (0)
#define VWAIT40 do { asm volatile("s_waitcnt vmcnt(40)" ::: "memory");   \
                     __builtin_amdgcn_sched_barrier(0); } while (0)
#define VWAIT0  do { asm volatile("s_waitcnt vmcnt(0)"  ::: "memory");   \
                     __builtin_amdgcn_sched_barrier(0); } while (0)

#define PROC16(R, Z, N) do {                                        \
        _Pragma("unroll")                                           \
        for (int _q = 0; _q < 8; ++_q) {                            \
            f16x2 rv = u2h(R[_q]), zv = u2h(Z[_q]), nv = u2h(N[_q]);\
            _Pragma("unroll")                                       \
            for (int _j = 0; _j < 2; ++_j) {                        \
                float ur = (float)rv[_j] + cr;                      \
                float uz = (float)zv[_j] + cz;                      \
                float un = (float)nv[_j] + cn;                      \
                float er = __builtin_amdgcn_exp2f(fmaf(whr, hv, ur)); \
                float r  = __builtin_amdgcn_rcpf(1.f + er);         \
                float ez = __builtin_amdgcn_exp2f(fmaf(whz, hv, uz)); \
                float z  = __builtin_amdgcn_rcpf(1.f + ez);         \
                float mn = fmaf(whn, hv, bhn);                      \
                float en = __builtin_amdgcn_exp2f(fmaf(r, mn, un)); \
                float q  = __builtin_amdgcn_rcpf(1.f + en);         \
                float hp1 = hv + 1.f;                               \
                hv = fmaf(z, fmaf(-2.f, q, hp1), fmaf(2.f, q, -1.f)); \
                *po = hv; po += so;                                 \
            }                                                       \
        }                                                           \
    } while (0)

    // Batches 0..127; even batches live in A regs, odd in B regs.
    LOADB(Ar, Az, An);                 // L0
    LOADB(Br, Bz, Bn);                 // L1
    VWAIT24;                           // queue 48 deep: L0 arrived
    PROC16(Ar, Az, An);                // batch 0, S0
    for (int i = 1; i <= 62; ++i) {
        LOADB(Ar, Az, An);             // L(2i)
        VWAIT40;                       // [L(2i-1),S(2i-2),L(2i)]: L(2i-1) done
        PROC16(Br, Bz, Bn);            // batch 2i-1
        LOADB(Br, Bz, Bn);             // L(2i+1)
        VWAIT40;                       // [L(2i),S(2i-1),L(2i+1)]: L(2i) done
        PROC16(Ar, Az, An);            // batch 2i
    }
    LOADB(Ar, Az, An);                 // L126
    VWAIT40;                           // L125 done
    PROC16(Br, Bz, Bn);                // batch 125
    LOADB(Br, Bz, Bn);                 // L127
    VWAIT40;                           // L126 done
    PROC16(Ar, Az, An);                // batch 126
    VWAIT0;                            // L127 done
    PROC16(Br, Bz, Bn);                // batch 127

    out[(size_t)T_LEN * so + (size_t)b * H_DIM + h] = hv;   // h_n
#undef LOADB
#undef VWAIT24
#undef VWAIT40
#undef VWAIT0
#undef PROC16
}

// ---------------------------------------------------------------------------
extern "C" void kernel_launch(void* const* d_in, const int* in_sizes, int n_in,
                              void* d_out, int out_size, void* d_ws, size_t ws_size,
                              hipStream_t stream) {
    const float* x   = (const float*)d_in[0];
    const float* Wih = (const float*)d_in[1];
    const float* bih = (const float*)d_in[2];
    const float* bhh = (const float*)d_in[3];
    const float* whh = (const float*)d_in[4];
    float* out = (float*)d_out;

    char* ws = (char*)d_ws;
    f16* gxP = (f16*)ws;                                       // 192 MiB packed
    f16* Xs  = (f16*)(ws + (size_t)M_ROWS*N3*sizeof(f16));     // 64 MiB
    f16* Wsc = Xs + (size_t)M_ROWS*I_DIM;                      // 384 KiB

    convert_x<<<2048, 256, 0, stream>>>(x, Xs);
    convert_w<<<(N3*I_DIM/8)/256, 256, 0, stream>>>(Wih, Wsc);
    gemm_gx<<<(M_ROWS/128)*(N3/128), 256, 0, stream>>>(Xs, Wsc, gxP);
    indgru_scan<<<BATCH*(H_DIM/64), 64, 0, stream>>>(gxP, bih, bhh, whh, out);
}